// Round 8
// baseline (8249.855 us; speedup 1.0000x reference)
//
#include <hip/hip_runtime.h>
#include <math.h>

// LSTMModel: 2048 sequential steps, 2x LSTMCell(H=512), LN(64) front, fc(512->1).
// R7: (1) loop-carried asm pins make weights GENUINELY register-resident (init-time
// KEEP was rematerialized away -> 256KB/block/step L2 restream ~1.9us); (2) barrier-
// free direct-tap polling: each thread polls its own 16 h-words from global in one
// 16-load asm (1 RTT MLP) -- no LDS, no __syncthreads, waves fully independent;
// (3) fc partial moved out of the recurrent loop (reduce_out reads h1 history).

#define H      512
#define G4     2048
#define WIN    64
#define STEPS  2048
#define NA     16      // layer-0 blocks (32 units each)
#define NB     32      // layer-1 blocks (16 units each)
#define TPB    512
#define POISON 0xFFFFFFFFu

typedef unsigned int u32x4 __attribute__((ext_vector_type(4)));
typedef unsigned int u32x2 __attribute__((ext_vector_type(2)));

__device__ __forceinline__ float sigf(float x)     { return 1.0f / (1.0f + __expf(-x)); }
__device__ __forceinline__ float tanhfast(float x) { return 2.0f / (1.0f + __expf(-2.0f * x)) - 1.0f; }

// ---- agent-scope packed publish ----
__device__ __forceinline__ void st4_sc01(unsigned int* p, u32x4 v) {
    asm volatile("global_store_dwordx4 %0, %1, off sc0 sc1" :: "v"(p), "v"(v));
}
__device__ __forceinline__ void st2_sc01(unsigned int* p, u32x2 v) {
    asm volatile("global_store_dwordx2 %0, %1, off sc0 sc1" :: "v"(p), "v"(v));
}

// ---- direct-tap poll: 16 strided words (stride 128B) in one asm, 1 waitcnt ----
__device__ __forceinline__ bool try16(const unsigned int* base, unsigned int r[16]) {
    asm volatile(
        "global_load_dword %0, %16, off sc0 sc1\n\t"
        "global_load_dword %1, %16, off offset:128 sc0 sc1\n\t"
        "global_load_dword %2, %16, off offset:256 sc0 sc1\n\t"
        "global_load_dword %3, %16, off offset:384 sc0 sc1\n\t"
        "global_load_dword %4, %16, off offset:512 sc0 sc1\n\t"
        "global_load_dword %5, %16, off offset:640 sc0 sc1\n\t"
        "global_load_dword %6, %16, off offset:768 sc0 sc1\n\t"
        "global_load_dword %7, %16, off offset:896 sc0 sc1\n\t"
        "global_load_dword %8, %16, off offset:1024 sc0 sc1\n\t"
        "global_load_dword %9, %16, off offset:1152 sc0 sc1\n\t"
        "global_load_dword %10, %16, off offset:1280 sc0 sc1\n\t"
        "global_load_dword %11, %16, off offset:1408 sc0 sc1\n\t"
        "global_load_dword %12, %16, off offset:1536 sc0 sc1\n\t"
        "global_load_dword %13, %16, off offset:1664 sc0 sc1\n\t"
        "global_load_dword %14, %16, off offset:1792 sc0 sc1\n\t"
        "global_load_dword %15, %16, off offset:1920 sc0 sc1\n\t"
        "s_waitcnt vmcnt(0)"
        : "=&v"(r[0]), "=&v"(r[1]), "=&v"(r[2]), "=&v"(r[3]),
          "=&v"(r[4]), "=&v"(r[5]), "=&v"(r[6]), "=&v"(r[7]),
          "=&v"(r[8]), "=&v"(r[9]), "=&v"(r[10]), "=&v"(r[11]),
          "=&v"(r[12]), "=&v"(r[13]), "=&v"(r[14]), "=&v"(r[15])
        : "v"(base));
    bool ok = true;
    #pragma unroll
    for (int i = 0; i < 16; ++i) ok &= (r[i] != POISON);
    return ok;
}

// ---- dual-base 32-tap poll (layer 1: h0 taps + h1 taps), 1 waitcnt ----
__device__ __forceinline__ bool try32(const unsigned int* pa, const unsigned int* pb,
                                      unsigned int r[32]) {
    asm volatile(
        "global_load_dword %0, %32, off sc0 sc1\n\t"
        "global_load_dword %1, %32, off offset:128 sc0 sc1\n\t"
        "global_load_dword %2, %32, off offset:256 sc0 sc1\n\t"
        "global_load_dword %3, %32, off offset:384 sc0 sc1\n\t"
        "global_load_dword %4, %32, off offset:512 sc0 sc1\n\t"
        "global_load_dword %5, %32, off offset:640 sc0 sc1\n\t"
        "global_load_dword %6, %32, off offset:768 sc0 sc1\n\t"
        "global_load_dword %7, %32, off offset:896 sc0 sc1\n\t"
        "global_load_dword %8, %32, off offset:1024 sc0 sc1\n\t"
        "global_load_dword %9, %32, off offset:1152 sc0 sc1\n\t"
        "global_load_dword %10, %32, off offset:1280 sc0 sc1\n\t"
        "global_load_dword %11, %32, off offset:1408 sc0 sc1\n\t"
        "global_load_dword %12, %32, off offset:1536 sc0 sc1\n\t"
        "global_load_dword %13, %32, off offset:1664 sc0 sc1\n\t"
        "global_load_dword %14, %32, off offset:1792 sc0 sc1\n\t"
        "global_load_dword %15, %32, off offset:1920 sc0 sc1\n\t"
        "global_load_dword %16, %33, off sc0 sc1\n\t"
        "global_load_dword %17, %33, off offset:128 sc0 sc1\n\t"
        "global_load_dword %18, %33, off offset:256 sc0 sc1\n\t"
        "global_load_dword %19, %33, off offset:384 sc0 sc1\n\t"
        "global_load_dword %20, %33, off offset:512 sc0 sc1\n\t"
        "global_load_dword %21, %33, off offset:640 sc0 sc1\n\t"
        "global_load_dword %22, %33, off offset:768 sc0 sc1\n\t"
        "global_load_dword %23, %33, off offset:896 sc0 sc1\n\t"
        "global_load_dword %24, %33, off offset:1024 sc0 sc1\n\t"
        "global_load_dword %25, %33, off offset:1152 sc0 sc1\n\t"
        "global_load_dword %26, %33, off offset:1280 sc0 sc1\n\t"
        "global_load_dword %27, %33, off offset:1408 sc0 sc1\n\t"
        "global_load_dword %28, %33, off offset:1536 sc0 sc1\n\t"
        "global_load_dword %29, %33, off offset:1664 sc0 sc1\n\t"
        "global_load_dword %30, %33, off offset:1792 sc0 sc1\n\t"
        "global_load_dword %31, %33, off offset:1920 sc0 sc1\n\t"
        "s_waitcnt vmcnt(0)"
        : "=&v"(r[0]),  "=&v"(r[1]),  "=&v"(r[2]),  "=&v"(r[3]),
          "=&v"(r[4]),  "=&v"(r[5]),  "=&v"(r[6]),  "=&v"(r[7]),
          "=&v"(r[8]),  "=&v"(r[9]),  "=&v"(r[10]), "=&v"(r[11]),
          "=&v"(r[12]), "=&v"(r[13]), "=&v"(r[14]), "=&v"(r[15]),
          "=&v"(r[16]), "=&v"(r[17]), "=&v"(r[18]), "=&v"(r[19]),
          "=&v"(r[20]), "=&v"(r[21]), "=&v"(r[22]), "=&v"(r[23]),
          "=&v"(r[24]), "=&v"(r[25]), "=&v"(r[26]), "=&v"(r[27]),
          "=&v"(r[28]), "=&v"(r[29]), "=&v"(r[30]), "=&v"(r[31])
        : "v"(pa), "v"(pb));
    bool ok = true;
    #pragma unroll
    for (int i = 0; i < 32; ++i) ok &= (r[i] != POISON);
    return ok;
}

// ---------------- LayerNorm over sliding windows (parallel over t) ----------------
__global__ void ln_kernel(const float* __restrict__ batch, const float* __restrict__ lnw,
                          const float* __restrict__ lnb, float* __restrict__ lnx) {
    int wave = threadIdx.x >> 6;
    int lane = threadIdx.x & 63;
    int t = blockIdx.x * 4 + wave;
    int src = t - 63 + lane;
    float v = (src >= 0) ? batch[src] : 0.0f;
    float s = v, ss = v * v;
    #pragma unroll
    for (int m = 32; m >= 1; m >>= 1) { s += __shfl_xor(s, m); ss += __shfl_xor(ss, m); }
    float mu   = s * (1.0f / 64.0f);
    float var  = ss * (1.0f / 64.0f) - mu * mu;
    float rstd = rsqrtf(var + 1e-5f);
    lnx[t * WIN + lane] = (v - mu) * rstd * lnw[lane] + lnb[lane];
}

// ------------- precomp0[t][r] = Wih0[r,:] . lnx[t,:] + bih0[r] + bhh0[r] ----------
__global__ __launch_bounds__(256) void precomp_kernel(
    const float* __restrict__ Wih0, const float* __restrict__ bih0,
    const float* __restrict__ bhh0, const float* __restrict__ lnx,
    float* __restrict__ pre) {
    __shared__ float Wt[64][65];
    __shared__ float Xt[64][64];
    int r0 = blockIdx.x * 64;
    int t0 = blockIdx.y * 64;
    for (int i = threadIdx.x; i < 4096; i += 256) Wt[i >> 6][i & 63] = Wih0[r0 * 64 + i];
    for (int i = threadIdx.x; i < 4096; i += 256) Xt[i >> 6][i & 63] = lnx[t0 * 64 + i];
    __syncthreads();
    int lane = threadIdx.x & 63;
    int wv   = threadIdx.x >> 6;
    int row  = r0 + lane;
    float bias = bih0[row] + bhh0[row];
    for (int j = 0; j < 16; ++j) {
        int tl = wv * 16 + j;
        float acc = bias;
        #pragma unroll 8
        for (int k = 0; k < 64; ++k) acc += Wt[lane][k] * Xt[tl][k];
        pre[(size_t)(t0 + tl) * G4 + row] = acc;
    }
}

// ---------------- persistent recurrent kernel: barrier-free waves ----------------
__global__ __launch_bounds__(TPB, 1) void recur_kernel(
    const float* __restrict__ Whh0,
    const float* __restrict__ Wih1, const float* __restrict__ Whh1,
    const float* __restrict__ bih1, const float* __restrict__ bhh1,
    const float* __restrict__ pre,
    unsigned int* h0u, unsigned int* h1u) { // [STEPS+1][H] histories, NaN-poisoned
    const int tid = threadIdx.x;
    const int s   = tid & 31;
    const int LG  = tid >> 5;    // 16 lane-groups of 32

    if (blockIdx.x < NA) {
        // ---------------- layer-0: 32 units/block, 4 units/wave ----------------
        const int u0 = blockIdx.x * 32;
        const int ul = 2 * LG + (s & 1);     // unit for gate lanes (s<2)
        const bool gl = (s < 2);
        // rows: j=0..7 -> gate=j&3, unit_local=2*LG+(j>>2)
        float w0[8][16];
        #pragma unroll
        for (int j = 0; j < 8; ++j) {
            int row = (j & 3) * H + u0 + 2 * LG + (j >> 2);
            #pragma unroll
            for (int i = 0; i < 16; ++i)
                w0[j][i] = Whh0[(size_t)row * H + i * 32 + s];
        }
        float c0 = 0.0f;
        float pr[4] = {0.f, 0.f, 0.f, 0.f};
        if (gl) {
            #pragma unroll
            for (int g = 0; g < 4; ++g) pr[g] = pre[(size_t)0 * G4 + g * H + u0 + ul];
        }

        for (int t = 0; t < STEPS; ++t) {
            // loop-carried pins: weights cannot be rematerialized from memory
            #pragma unroll
            for (int j = 0; j < 8; ++j) {
                #pragma unroll
                for (int i = 0; i < 16; ++i) asm("" : "+v"(w0[j][i]));
            }
            // prefetch next step's pre (consumed next iteration)
            float prn[4] = {0.f, 0.f, 0.f, 0.f};
            {
                const int tn = (t + 1) & (STEPS - 1);
                if (gl) {
                    #pragma unroll
                    for (int g = 0; g < 4; ++g) prn[g] = pre[(size_t)tn * G4 + g * H + u0 + ul];
                }
            }
            // direct-tap poll: h0[t*H + i*32 + s], i=0..15
            unsigned int r[16];
            if (t > 0) {
                const unsigned int* base = h0u + (size_t)t * H + s;
                while (!try16(base, r)) {}
            } else {
                #pragma unroll
                for (int i = 0; i < 16; ++i) r[i] = 0u;   // h(-1)=0 (bits of 0.0f)
            }
            float hf[16];
            #pragma unroll
            for (int i = 0; i < 16; ++i) hf[i] = __uint_as_float(r[i]);

            float acc[8];
            #pragma unroll
            for (int j = 0; j < 8; ++j) {
                float a = 0.0f;
                #pragma unroll
                for (int i = 0; i < 16; ++i) a += w0[j][i] * hf[i];
                acc[j] = a;
            }
            #pragma unroll
            for (int m = 16; m >= 1; m >>= 1) {
                #pragma unroll
                for (int j = 0; j < 8; ++j) acc[j] += __shfl_xor(acc[j], m);
            }
            float hnew = 0.0f;
            if (gl) {
                const int base4 = (s & 1) * 4;
                float iv = sigf(acc[base4 + 0] + pr[0]);
                float fv = sigf(acc[base4 + 1] + pr[1]);
                float gv = tanhfast(acc[base4 + 2] + pr[2]);
                float ov = sigf(acc[base4 + 3] + pr[3]);
                c0 = fv * c0 + iv * gv;
                hnew = ov * tanhfast(c0);
            }
            // wave-gather: units 4w..4w+3 on wave-lanes 0,1,32,33 -> one x4 packet
            unsigned int hb = __float_as_uint(hnew);
            unsigned int b0 = __shfl(hb, 0), b1 = __shfl(hb, 1);
            unsigned int b2 = __shfl(hb, 32), b3 = __shfl(hb, 33);
            if ((tid & 63) == 0) {
                u32x4 pk; pk.x = b0; pk.y = b1; pk.z = b2; pk.w = b3;
                st4_sc01(h0u + (size_t)(t + 1) * H + u0 + (tid >> 6) * 4, pk);
            }
            #pragma unroll
            for (int g = 0; g < 4; ++g) pr[g] = prn[g];
        }
    } else {
        // ---------------- layer-1: 16 units/block, 2 units/wave ----------------
        const int b1i = blockIdx.x - NA;
        const int u0 = b1i * 16;
        // rows: j = gate 0..3, unit_local = LG
        float w1[4][16], w2[4][16], bias[4];
        #pragma unroll
        for (int j = 0; j < 4; ++j) {
            int row = j * H + u0 + LG;
            bias[j] = bih1[row] + bhh1[row];
            #pragma unroll
            for (int i = 0; i < 16; ++i) {
                w1[j][i] = Wih1[(size_t)row * H + i * 32 + s];
                w2[j][i] = Whh1[(size_t)row * H + i * 32 + s];
            }
        }
        float c1 = 0.0f;

        for (int t = 0; t < STEPS; ++t) {
            #pragma unroll
            for (int j = 0; j < 4; ++j) {
                #pragma unroll
                for (int i = 0; i < 16; ++i) {
                    asm("" : "+v"(w1[j][i]));
                    asm("" : "+v"(w2[j][i]));
                }
            }
            unsigned int r[32];
            const unsigned int* pa = h0u + (size_t)(t + 1) * H + s;
            if (t > 0) {
                const unsigned int* pb = h1u + (size_t)t * H + s;
                while (!try32(pa, pb, r)) {}
            } else {
                while (!try16(pa, r)) {}
                #pragma unroll
                for (int i = 16; i < 32; ++i) r[i] = 0u;
            }
            float ha[16], hb1[16];
            #pragma unroll
            for (int i = 0; i < 16; ++i) { ha[i] = __uint_as_float(r[i]); hb1[i] = __uint_as_float(r[16 + i]); }

            float acc[4];
            #pragma unroll
            for (int j = 0; j < 4; ++j) {
                float a = 0.0f;
                #pragma unroll
                for (int i = 0; i < 16; ++i) a += w1[j][i] * ha[i] + w2[j][i] * hb1[i];
                acc[j] = a;
            }
            #pragma unroll
            for (int m = 16; m >= 1; m >>= 1) {
                #pragma unroll
                for (int j = 0; j < 4; ++j) acc[j] += __shfl_xor(acc[j], m);
            }
            float hnew = 0.0f;
            if (s == 0) {
                float iv = sigf(acc[0] + bias[0]);
                float fv = sigf(acc[1] + bias[1]);
                float gv = tanhfast(acc[2] + bias[2]);
                float ov = sigf(acc[3] + bias[3]);
                c1 = fv * c1 + iv * gv;
                hnew = ov * tanhfast(c1);
            }
            // wave-gather: units 2w,2w+1 on wave-lanes 0,32 -> one x2 packet
            unsigned int hb = __float_as_uint(hnew);
            unsigned int b0 = __shfl(hb, 0), b2 = __shfl(hb, 32);
            if ((tid & 63) == 0) {
                u32x2 pk; pk.x = b0; pk.y = b2;
                st2_sc01(h1u + (size_t)(t + 1) * H + u0 + (tid >> 6) * 2, pk);
            }
        }
    }
}

// ---------------- out[t] = fc(relu(h1[t+1])) from the h1 history ----------------
__global__ __launch_bounds__(TPB) void reduce_out(
    const unsigned int* __restrict__ h1u, const float* __restrict__ fcw,
    const float* __restrict__ fcb, float* __restrict__ out) {
    int t = blockIdx.x;
    int tid = threadIdx.x;               // 512 threads
    float h = __uint_as_float(h1u[(size_t)(t + 1) * H + tid]);
    float v = fmaxf(h, 0.0f) * fcw[tid];
    #pragma unroll
    for (int m = 32; m >= 1; m >>= 1) v += __shfl_xor(v, m);
    __shared__ float ws8[8];
    if ((tid & 63) == 0) ws8[tid >> 6] = v;
    __syncthreads();
    if (tid == 0) {
        float ssum = 0.0f;
        #pragma unroll
        for (int i = 0; i < 8; ++i) ssum += ws8[i];
        out[t] = ssum + fcb[0];
    }
}

extern "C" void kernel_launch(void* const* d_in, const int* in_sizes, int n_in,
                              void* d_out, int out_size, void* d_ws, size_t ws_size,
                              hipStream_t stream) {
    const float* batch = (const float*)d_in[0];
    const float* Wih0  = (const float*)d_in[1];
    const float* Whh0  = (const float*)d_in[2];
    const float* bih0  = (const float*)d_in[3];
    const float* bhh0  = (const float*)d_in[4];
    const float* Wih1  = (const float*)d_in[5];
    const float* Whh1  = (const float*)d_in[6];
    const float* bih1  = (const float*)d_in[7];
    const float* bhh1  = (const float*)d_in[8];
    const float* lnw   = (const float*)d_in[9];
    const float* lnb   = (const float*)d_in[10];
    const float* fcw   = (const float*)d_in[11];
    const float* fcb   = (const float*)d_in[12];
    float* out = (float*)d_out;

    // workspace layout (~25 MB)
    float*        ws   = (float*)d_ws;
    float*        pre  = ws;                                   // 2048*2048
    float*        lnx  = pre + (size_t)STEPS * G4;             // 2048*64
    unsigned int* h0u  = (unsigned int*)(lnx + (size_t)STEPS * WIN);  // 2049*512
    unsigned int* h1u  = h0u + (size_t)(STEPS + 1) * H;        // 2049*512

    // poison both h histories (NaN pattern); slot 0 handled by t==0 branch in-kernel
    (void)hipMemsetAsync(h0u, 0xFF, (size_t)2 * (STEPS + 1) * H * sizeof(unsigned int), stream);

    ln_kernel<<<dim3(STEPS / 4), dim3(256), 0, stream>>>(batch, lnw, lnb, lnx);
    precomp_kernel<<<dim3(G4 / 64, STEPS / 64), dim3(256), 0, stream>>>(Wih0, bih0, bhh0, lnx, pre);
    recur_kernel<<<dim3(NA + NB), dim3(TPB), 0, stream>>>(Whh0, Wih1, Whh1, bih1, bhh1,
                                                          pre, h0u, h1u);
    reduce_out<<<dim3(STEPS), dim3(TPB), 0, stream>>>(h1u, fcw, fcb, out);
}

// Round 10
// 5950.619 us; speedup vs baseline: 1.3864x; 1.3864x over previous
//
#include <hip/hip_runtime.h>
#include <math.h>

// LSTMModel: 2048 sequential steps, 2x LSTMCell(H=512), LN(64) front, fc(512->1).
// R9: make weights ACTUALLY register-resident by shrinking them to 32 floats/thread
// (R6-R8 proved 128/thread cannot be pinned; allocator restreams 256KB/block/step).
// L0: 64 blocks x 8 units (2 rows/group, gates resolve within one wave, 1 barrier).
// L1: 128 blocks x 4 units (1 row/group, LDS gate exchange, 2 barriers).
// Sync: proven R2/R6 skeleton -- NaN data-as-flag, agent-scope x4 polls -> LDS,
// parity double-buffer, scalar sc01 publishes. No async-register prefetch (R8 bug:
// regalloc copies/spills in-flight load dest regs between issue and fence).

#define H      512
#define G4     2048
#define WIN    64
#define STEPS  2048
#define NL0B   64      // layer-0 blocks (8 units each)
#define NL1B   128     // layer-1 blocks (4 units each)
#define TPB    512
#define POISON 0xFFFFFFFFu

typedef unsigned int u32x4 __attribute__((ext_vector_type(4)));
typedef float        f32x4 __attribute__((ext_vector_type(4)));

__device__ __forceinline__ float sigf(float x)     { return 1.0f / (1.0f + __expf(-x)); }
__device__ __forceinline__ float tanhfast(float x) { return 2.0f / (1.0f + __expf(-2.0f * x)) - 1.0f; }

// ---- agent-scope helpers (no "memory" clobber: volatile asms keep mutual order;
//      polled value IS the data; publishes are data-dependent) ----
__device__ __forceinline__ u32x4 ld4_sc01(const unsigned int* p) {
    u32x4 v;
    asm volatile("global_load_dwordx4 %0, %1, off sc0 sc1\n\ts_waitcnt vmcnt(0)"
                 : "=&v"(v) : "v"(p));
    return v;
}
__device__ __forceinline__ void st1_sc01(unsigned int* p, unsigned int v) {
    asm volatile("global_store_dword %0, %1, off sc0 sc1" :: "v"(p), "v"(v));
}
__device__ __forceinline__ bool ok4(u32x4 v) {
    return v.x != POISON && v.y != POISON && v.z != POISON && v.w != POISON;
}
__device__ __forceinline__ void lds_put4(float* dst, u32x4 v) {
    float4 f;
    f.x = __uint_as_float(v.x); f.y = __uint_as_float(v.y);
    f.z = __uint_as_float(v.z); f.w = __uint_as_float(v.w);
    *(float4*)dst = f;
}

// ---------------- LayerNorm over sliding windows (parallel over t) ----------------
__global__ void ln_kernel(const float* __restrict__ batch, const float* __restrict__ lnw,
                          const float* __restrict__ lnb, float* __restrict__ lnx) {
    int wave = threadIdx.x >> 6;
    int lane = threadIdx.x & 63;
    int t = blockIdx.x * 4 + wave;
    int src = t - 63 + lane;
    float v = (src >= 0) ? batch[src] : 0.0f;
    float s = v, ss = v * v;
    #pragma unroll
    for (int m = 32; m >= 1; m >>= 1) { s += __shfl_xor(s, m); ss += __shfl_xor(ss, m); }
    float mu   = s * (1.0f / 64.0f);
    float var  = ss * (1.0f / 64.0f) - mu * mu;
    float rstd = rsqrtf(var + 1e-5f);
    lnx[t * WIN + lane] = (v - mu) * rstd * lnw[lane] + lnb[lane];
}

// ---- precomp, UNIT-MAJOR layout: pre[t*2048 + unit*4 + gate] ----
__global__ __launch_bounds__(256) void precomp_kernel(
    const float* __restrict__ Wih0, const float* __restrict__ bih0,
    const float* __restrict__ bhh0, const float* __restrict__ lnx,
    float* __restrict__ pre) {
    __shared__ float Wt[64][65];
    __shared__ float Xt[64][64];
    int r0 = blockIdx.x * 64;
    int t0 = blockIdx.y * 64;
    for (int i = threadIdx.x; i < 4096; i += 256) Wt[i >> 6][i & 63] = Wih0[r0 * 64 + i];
    for (int i = threadIdx.x; i < 4096; i += 256) Xt[i >> 6][i & 63] = lnx[t0 * 64 + i];
    __syncthreads();
    int lane = threadIdx.x & 63;
    int wv   = threadIdx.x >> 6;
    int row  = r0 + lane;                      // gate-major: gate*512 + unit
    int oidx = (row & 511) * 4 + (row >> 9);   // unit-major: unit*4 + gate
    float bias = bih0[row] + bhh0[row];
    for (int j = 0; j < 16; ++j) {
        int tl = wv * 16 + j;
        float acc = bias;
        #pragma unroll 8
        for (int k = 0; k < 64; ++k) acc += Wt[lane][k] * Xt[tl][k];
        pre[(size_t)(t0 + tl) * G4 + oidx] = acc;
    }
}

// ---------------- persistent recurrent kernel ----------------
__global__ __launch_bounds__(TPB) void recur_kernel(
    const float* __restrict__ Whh0,
    const float* __restrict__ Wih1, const float* __restrict__ Whh1,
    const float* __restrict__ bih1, const float* __restrict__ bhh1,
    const float* __restrict__ pre,
    unsigned int* h0u, unsigned int* h1u) { // [STEPS+1][H] histories, NaN-poisoned
    const int tid = threadIdx.x;
    const int s   = tid & 31;
    const int LG  = tid >> 5;    // 16 lane-groups of 32

    if (blockIdx.x < NL0B) {
        // -------- layer-0: 8 units/block; unit = wave; 2 rows/lane-group --------
        __shared__ float hA[2][H];
        const int u0 = blockIdx.x * 8;
        const int u  = tid >> 6;              // wave index = unit-local
        // rows r = 2*LG + j : gate = r&3, unit_local = r>>2
        float w0[2][16];
        #pragma unroll
        for (int j = 0; j < 2; ++j) {
            int r   = 2 * LG + j;
            int row = (r & 3) * H + u0 + (r >> 2);
            #pragma unroll
            for (int i = 0; i < 16; ++i) w0[j][i] = Whh0[(size_t)row * H + i * 32 + s];
        }
        float c0 = 0.0f;

        for (int t = 0; t < STEPS; ++t) {
            const int pb = t & 1;
            // pre for this wave's unit (same addr across wave -> broadcast);
            // issued before the poll so its latency hides under the wait
            f32x4 prv = *(const f32x4*)(pre + (size_t)t * G4 + (u0 + u) * 4);
            if (tid < 128) {
                if (t > 0) {
                    const unsigned int* p = h0u + (size_t)t * H + tid * 4;
                    u32x4 v;
                    do { v = ld4_sc01(p); } while (!ok4(v));
                    lds_put4(&hA[pb][tid * 4], v);
                } else {
                    *(float4*)&hA[pb][tid * 4] = make_float4(0.f, 0.f, 0.f, 0.f);
                }
            }
            __syncthreads();

            float acc0 = 0.0f, acc1 = 0.0f;
            #pragma unroll
            for (int i = 0; i < 16; ++i) {
                float hv = hA[pb][i * 32 + s];
                acc0 += w0[0][i] * hv;
                acc1 += w0[1][i] * hv;
            }
            #pragma unroll
            for (int m = 16; m >= 1; m >>= 1) {
                acc0 += __shfl_xor(acc0, m);
                acc1 += __shfl_xor(acc1, m);
            }
            // lower half-group: gates i,f ; upper half-group (lane 32): g,o
            float gacc = __shfl(acc0, 32);
            float oacc = __shfl(acc1, 32);
            if ((tid & 63) == 0) {
                float iv = sigf(acc0 + prv.x);
                float fv = sigf(acc1 + prv.y);
                float gv = tanhfast(gacc + prv.z);
                float ov = sigf(oacc + prv.w);
                c0 = fv * c0 + iv * gv;
                float hnew = ov * tanhfast(c0);
                st1_sc01(h0u + (size_t)(t + 1) * H + u0 + u, __float_as_uint(hnew));
            }
        }
    } else {
        // -------- layer-1: 4 units/block; 1 row/lane-group; LDS gate exchange --------
        __shared__ float hA2[2][H];
        __shared__ float hB2[2][H];
        __shared__ float glds[16];
        const int b1 = blockIdx.x - NL0B;
        const int u0 = b1 * 4;
        // group LG: gate = LG&3, unit_local = LG>>2
        const int row = (LG & 3) * H + u0 + (LG >> 2);
        float w1[16], w2[16];
        #pragma unroll
        for (int i = 0; i < 16; ++i) {
            w1[i] = Wih1[(size_t)row * H + i * 32 + s];
            w2[i] = Whh1[(size_t)row * H + i * 32 + s];
        }
        const float rbias = bih1[row] + bhh1[row];
        float c1 = 0.0f;

        for (int t = 0; t < STEPS; ++t) {
            const int pb = t & 1;
            if (tid < 128) {
                const unsigned int* pa = h0u + (size_t)(t + 1) * H + tid * 4;
                u32x4 va; bool da = false;
                if (t > 0) {
                    const unsigned int* pbp = h1u + (size_t)t * H + tid * 4;
                    u32x4 vb; bool db = false;
                    do {
                        if (!da) { va = ld4_sc01(pa); da = ok4(va); }
                        if (!db) { vb = ld4_sc01(pbp); db = ok4(vb); }
                    } while (!(da && db));
                    lds_put4(&hB2[pb][tid * 4], vb);
                } else {
                    do { va = ld4_sc01(pa); da = ok4(va); } while (!da);
                    *(float4*)&hB2[pb][tid * 4] = make_float4(0.f, 0.f, 0.f, 0.f);
                }
                lds_put4(&hA2[pb][tid * 4], va);
            }
            __syncthreads();

            float acc = 0.0f;
            #pragma unroll
            for (int i = 0; i < 16; ++i)
                acc += w1[i] * hA2[pb][i * 32 + s] + w2[i] * hB2[pb][i * 32 + s];
            #pragma unroll
            for (int m = 16; m >= 1; m >>= 1) acc += __shfl_xor(acc, m);
            if (s == 0) glds[LG] = acc + rbias;
            __syncthreads();
            if (tid < 4) {
                float iv = sigf(glds[4 * tid + 0]);
                float fv = sigf(glds[4 * tid + 1]);
                float gv = tanhfast(glds[4 * tid + 2]);
                float ov = sigf(glds[4 * tid + 3]);
                c1 = fv * c1 + iv * gv;
                float hnew = ov * tanhfast(c1);
                st1_sc01(h1u + (size_t)(t + 1) * H + u0 + tid, __float_as_uint(hnew));
            }
        }
    }
}

// ---------------- out[t] = fc(relu(h1[t+1])) from the h1 history ----------------
__global__ __launch_bounds__(TPB) void reduce_out(
    const unsigned int* __restrict__ h1u, const float* __restrict__ fcw,
    const float* __restrict__ fcb, float* __restrict__ out) {
    int t = blockIdx.x;
    int tid = threadIdx.x;               // 512 threads
    float h = __uint_as_float(h1u[(size_t)(t + 1) * H + tid]);
    float v = fmaxf(h, 0.0f) * fcw[tid];
    #pragma unroll
    for (int m = 32; m >= 1; m >>= 1) v += __shfl_xor(v, m);
    __shared__ float ws8[8];
    if ((tid & 63) == 0) ws8[tid >> 6] = v;
    __syncthreads();
    if (tid == 0) {
        float ssum = 0.0f;
        #pragma unroll
        for (int i = 0; i < 8; ++i) ssum += ws8[i];
        out[t] = ssum + fcb[0];
    }
}

extern "C" void kernel_launch(void* const* d_in, const int* in_sizes, int n_in,
                              void* d_out, int out_size, void* d_ws, size_t ws_size,
                              hipStream_t stream) {
    const float* batch = (const float*)d_in[0];
    const float* Wih0  = (const float*)d_in[1];
    const float* Whh0  = (const float*)d_in[2];
    const float* bih0  = (const float*)d_in[3];
    const float* bhh0  = (const float*)d_in[4];
    const float* Wih1  = (const float*)d_in[5];
    const float* Whh1  = (const float*)d_in[6];
    const float* bih1  = (const float*)d_in[7];
    const float* bhh1  = (const float*)d_in[8];
    const float* lnw   = (const float*)d_in[9];
    const float* lnb   = (const float*)d_in[10];
    const float* fcw   = (const float*)d_in[11];
    const float* fcb   = (const float*)d_in[12];
    float* out = (float*)d_out;

    // workspace layout (~17 MB)
    float*        ws   = (float*)d_ws;
    float*        pre  = ws;                                   // 2048*2048 (16 MB)
    float*        lnx  = pre + (size_t)STEPS * G4;             // 2048*64
    unsigned int* h0u  = (unsigned int*)(lnx + (size_t)STEPS * WIN);  // 2049*512
    unsigned int* h1u  = h0u + (size_t)(STEPS + 1) * H;        // 2049*512

    // poison both h histories (NaN pattern); slot 0 handled by t==0 branch in-kernel
    (void)hipMemsetAsync(h0u, 0xFF, (size_t)2 * (STEPS + 1) * H * sizeof(unsigned int), stream);

    ln_kernel<<<dim3(STEPS / 4), dim3(256), 0, stream>>>(batch, lnw, lnb, lnx);
    precomp_kernel<<<dim3(G4 / 64, STEPS / 64), dim3(256), 0, stream>>>(Wih0, bih0, bhh0, lnx, pre);
    recur_kernel<<<dim3(NL0B + NL1B), dim3(TPB), 0, stream>>>(Whh0, Wih1, Whh1, bih1, bhh1,
                                                              pre, h0u, h1u);
    reduce_out<<<dim3(STEPS), dim3(TPB), 0, stream>>>(h1u, fcw, fcb, out);
}